// Round 6
// baseline (1067.777 us; speedup 1.0000x reference)
//
#include <hip/hip_runtime.h>

typedef __bf16 bf16;
typedef __attribute__((ext_vector_type(8))) __bf16 bf16x8;
typedef __attribute__((ext_vector_type(4))) __bf16 bf16x4;
typedef __attribute__((ext_vector_type(4))) float f32x4;

#define B_ 16
#define C_ 768
#define T_ 1024
#define S_ 12
#define NNEG_ 10
#define NCOPY 11
#define NPRED_ROWS 195360            // 16 * sum_{s=0..11}(1023-s)
#define NPRED (NPRED_ROWS * NCOPY)   // 2148960

// ---------- W [C][C][S] fp32 -> WtT [S][D=C][C] bf16 ----------
__global__ void k_wt(const float* __restrict__ W, bf16* __restrict__ WtT) {
    int id = blockIdx.x * blockDim.x + threadIdx.x;   // id = d*768 + c
    if (id >= C_ * C_) return;
    int d = id / C_, c = id % C_;
    const float* src = W + ((size_t)c * C_ + d) * S_;
#pragma unroll
    for (int s = 0; s < S_; ++s)
        WtT[(size_t)s * C_ * C_ + id] = (bf16)src[s];
}

// ---------- x,y [16][C][T] fp32 (batches b0..b0+cb) -> xTc,yTc [cb][T][C] bf16 ----------
__global__ void k_tr2(const float* __restrict__ x, const float* __restrict__ y,
                      bf16* __restrict__ xTc, bf16* __restrict__ yTc, int b0, int cb) {
    __shared__ float tile[32][33];
    int zz = blockIdx.z;
    const float* src = (zz < cb) ? x : y;
    bf16* dst = (zz < cb) ? xTc : yTc;
    int bb = (zz < cb) ? zz : zz - cb;
    int b = b0 + bb;
    int c0 = blockIdx.y * 32, t0 = blockIdx.x * 32;
    int tx = threadIdx.x & 31, ty = threadIdx.x >> 5;  // ty 0..7
#pragma unroll
    for (int i = 0; i < 4; ++i)
        tile[ty + i * 8][tx] = src[((size_t)b * C_ + c0 + ty + i * 8) * T_ + t0 + tx];
    __syncthreads();
#pragma unroll
    for (int i = 0; i < 4; ++i)
        dst[((size_t)bb * T_ + t0 + ty + i * 8) * C_ + c0 + tx] = (bf16)tile[tx][ty + i * 8];
}

// ---------- Phase 1: P[bb][t][n] = sum_c WtT[n][c]*xTc[bb][t][c] + bias[n%768]
// LDS-FREE: MFMA fragments loaded directly from global (L2/L3-hot operands).
// No __syncthreads in the whole kernel -> no synchronized drain phases.
// Fragment pattern per wave-instr: 16 rows x 64 contiguous bytes (coalesced).
// MFMA 16x16x32; M-dim = n (WtT rows), N-dim = t (xTc rows). 128x128 per block.
__global__ __launch_bounds__(256, 3) void k_gemm(
    const bf16* __restrict__ xTc, const bf16* __restrict__ WtT,
    const float* __restrict__ bias, bf16* __restrict__ P)
{
    const int nblk = blockIdx.x;   // n tile (n = s*768+d)
    const int tblk = blockIdx.y;   // t tile
    const int bb   = blockIdx.z;
    const int tid  = threadIdx.x;
    const int wave = tid >> 6, lane = tid & 63;
    const int mw = wave >> 1, nw = wave & 1;     // n-half / t-half of 128x128
    const int quad = lane >> 4, l15 = lane & 15;

    // A[m][k]: m = lane&15, k = quad*8 + j  -> row (..+l15), bytes quad*16..+16
    const bf16* aB = WtT + (size_t)(nblk * 128 + mw * 64 + l15) * C_ + quad * 8;
    const bf16* bB = xTc + ((size_t)bb * T_ + tblk * 128 + nw * 64 + l15) * C_ + quad * 8;

    f32x4 acc[4][4] = {};

#pragma unroll
    for (int k0 = 0; k0 < C_; k0 += 32) {
        bf16x8 af[4], bfr[4];
#pragma unroll
        for (int i = 0; i < 4; ++i) af[i]  = *(const bf16x8*)(aB + (size_t)i * 16 * C_ + k0);
#pragma unroll
        for (int j = 0; j < 4; ++j) bfr[j] = *(const bf16x8*)(bB + (size_t)j * 16 * C_ + k0);
#pragma unroll
        for (int i = 0; i < 4; ++i)
#pragma unroll
            for (int j = 0; j < 4; ++j)
                acc[i][j] = __builtin_amdgcn_mfma_f32_16x16x32_bf16(af[i], bfr[j], acc[i][j], 0, 0, 0);
    }

    // epilogue: D row = n-local (quad*4+r, 4 consecutive), col = t-local (l15).
#pragma unroll
    for (int i = 0; i < 4; ++i) {
        const int nb = mw * 64 + i * 16 + quad * 4;
        const f32x4 bv = *(const f32x4*)&bias[(nblk % 6) * 128 + nb];
#pragma unroll
        for (int j = 0; j < 4; ++j) {
            const int t = tblk * 128 + nw * 64 + j * 16 + l15;
            bf16x4 v;
#pragma unroll
            for (int r = 0; r < 4; ++r) v[r] = (bf16)(acc[i][j][r] + bv[r]);
            *(bf16x4*)&P[((size_t)bb * T_ + t) * (size_t)(S_ * C_) + (size_t)nblk * 128 + nb] = v;
        }
    }
}

// ---------- Phase 2: one wave per (bb, tp). p[s][n] = sum_d proj[t=tp-1-s][s][d]*tar[n][d]
// Lane l15==11 also writes the zero labels for its 12 output rows.
__global__ __launch_bounds__(256) void k_pred(
    const bf16* __restrict__ P, const bf16* __restrict__ yTc,
    const int* __restrict__ neg, float* __restrict__ out, int b0)
{
    const int widx = (blockIdx.x << 2) + (threadIdx.x >> 6);
    const int lane = threadIdx.x & 63;
    const int bb = widx >> 10, tp = widx & 1023;
    const int b = b0 + bb;
    const int quad = lane >> 4, l15 = lane & 15;

    // A row: m = s (pad rows clamped; their outputs are never stored)
    int sA = l15 < S_ ? l15 : S_ - 1;
    int tA = tp - 1 - sA;
    if (tA < 0) tA = 0;
    const bf16* arow = P + ((size_t)bb * T_ + tA) * (S_ * C_) + sA * C_ + quad * 8;

    // B row: n = copy (pad clamped)
    int ridx;
    if (l15 == 0)            ridx = bb * T_ + tp;
    else if (l15 < NCOPY)    ridx = neg[(size_t)b * (NNEG_ * T_) + (l15 - 1) * T_ + tp] - b0 * T_;
    else                     ridx = bb * T_ + tp;
    const bf16* brow = yTc + (size_t)ridx * C_ + quad * 8;

    f32x4 acc = {};
#pragma unroll 4
    for (int kt = 0; kt < C_ / 32; ++kt) {
        bf16x8 av = *(const bf16x8*)(arow + kt * 32);
        bf16x8 bv = *(const bf16x8*)(brow + kt * 32);
        acc = __builtin_amdgcn_mfma_f32_16x16x32_bf16(av, bv, acc, 0, 0, 0);
    }

#pragma unroll
    for (int r = 0; r < 4; ++r) {
        int s = quad * 4 + r;
        int t = tp - 1 - s;
        if (s < S_ && t >= 0) {
            int rowbase = s * (T_ - 1) - (s * (s - 1)) / 2;
            size_t row = (size_t)(rowbase + t) * B_ + b;
            if (l15 < NCOPY)       out[row * NCOPY + l15] = acc[r];
            else if (l15 == NCOPY) out[NPRED + row] = 0.0f;   // labels
        }
    }
}

extern "C" void kernel_launch(void* const* d_in, const int* in_sizes, int n_in,
                              void* d_out, int out_size, void* d_ws, size_t ws_size,
                              hipStream_t stream) {
    const float* x    = (const float*)d_in[0];
    const float* y    = (const float*)d_in[1];
    const float* W    = (const float*)d_in[2];
    const float* bias = (const float*)d_in[3];
    const int*   neg  = (const int*)d_in[4];
    float* out = (float*)d_out;

    const size_t offW    = (size_t)S_ * C_ * C_ * 2;        // 14,155,776
    const size_t perb_xy = (size_t)T_ * C_ * 2;             // 1,572,864
    const size_t perb_p  = (size_t)T_ * S_ * C_ * 2;        // 18,874,368
    const size_t perb    = 2 * perb_xy + perb_p;

    int bchunk = (int)((ws_size - offW) / perb);
    if (bchunk < 1) bchunk = 1;
    if (bchunk > B_) bchunk = B_;

    char* ws = (char*)d_ws;
    bf16* WtT = (bf16*)ws;
    bf16* xTc = (bf16*)(ws + offW);
    bf16* yTc = (bf16*)(ws + offW + (size_t)bchunk * perb_xy);
    bf16* P   = (bf16*)(ws + offW + (size_t)bchunk * perb_xy * 2);

    k_wt<<<dim3((C_ * C_ + 255) / 256), 256, 0, stream>>>(W, WtT);

    for (int b0 = 0; b0 < B_;) {
        int cb = bchunk < (B_ - b0) ? bchunk : (B_ - b0);
        k_tr2<<<dim3(T_ / 32, C_ / 32, 2 * cb), 256, 0, stream>>>(x, y, xTc, yTc, b0, cb);
        k_gemm<<<dim3(72, 8, cb), 256, 0, stream>>>(xTc, WtT, bias, P);
        k_pred<<<dim3(cb * 256), 256, 0, stream>>>(P, yTc, neg, out, b0);
        b0 += cb;
    }
}

// Round 7
// 663.493 us; speedup vs baseline: 1.6093x; 1.6093x over previous
//
#include <hip/hip_runtime.h>

typedef __bf16 bf16;
typedef __attribute__((ext_vector_type(8))) __bf16 bf16x8;
typedef __attribute__((ext_vector_type(4))) __bf16 bf16x4;
typedef __attribute__((ext_vector_type(4))) float f32x4;

#define B_ 16
#define C_ 768
#define T_ 1024
#define S_ 12
#define NNEG_ 10
#define NCOPY 11
#define NPRED_ROWS 195360            // 16 * sum_{s=0..11}(1023-s)
#define NPRED (NPRED_ROWS * NCOPY)   // 2148960

__device__ __forceinline__ void gload16(const void* g, void* l) {
    __builtin_amdgcn_global_load_lds(
        (__attribute__((address_space(1))) void*)g,
        (__attribute__((address_space(3))) void*)l, 16, 0, 0);
}

// ---------- W [C][C][S] fp32 -> WtT [S][D=C][C] bf16 ----------
__global__ void k_wt(const float* __restrict__ W, bf16* __restrict__ WtT) {
    int id = blockIdx.x * blockDim.x + threadIdx.x;   // id = d*768 + c
    if (id >= C_ * C_) return;
    int d = id / C_, c = id % C_;
    const float* src = W + ((size_t)c * C_ + d) * S_;
#pragma unroll
    for (int s = 0; s < S_; ++s)
        WtT[(size_t)s * C_ * C_ + id] = (bf16)src[s];
}

// ---------- x,y [16][C][T] fp32 (batches b0..b0+cb) -> xTc,yTc [cb][T][C] bf16 ----------
__global__ void k_tr2(const float* __restrict__ x, const float* __restrict__ y,
                      bf16* __restrict__ xTc, bf16* __restrict__ yTc, int b0, int cb) {
    __shared__ float tile[32][33];
    int zz = blockIdx.z;
    const float* src = (zz < cb) ? x : y;
    bf16* dst = (zz < cb) ? xTc : yTc;
    int bb = (zz < cb) ? zz : zz - cb;
    int b = b0 + bb;
    int c0 = blockIdx.y * 32, t0 = blockIdx.x * 32;
    int tx = threadIdx.x & 31, ty = threadIdx.x >> 5;  // ty 0..7
#pragma unroll
    for (int i = 0; i < 4; ++i)
        tile[ty + i * 8][tx] = src[((size_t)b * C_ + c0 + ty + i * 8) * T_ + t0 + tx];
    __syncthreads();
#pragma unroll
    for (int i = 0; i < 4; ++i)
        dst[((size_t)bb * T_ + t0 + ty + i * 8) * C_ + c0 + tx] = (bf16)tile[tx][ty + i * 8];
}

// ---------- Phase 1: P[bb][t][n] = sum_c WtT[n][c]*xTc[bb][t][c] + bias[n%768]
// MFMA 16x16x32; M-dim = n (WtT rows), N-dim = t (xTc rows).
// 128n x 256t tile, 512 threads (8 waves as 2n x 4t, 64x64 each), BK=32.
// 128 MFMA per 24 KB staged per iteration (2.7x round-2's MFMA:staging ratio).
__global__ __launch_bounds__(512, 4) void k_gemm(
    const bf16* __restrict__ xTc, const bf16* __restrict__ WtT,
    const float* __restrict__ bias, bf16* __restrict__ P)
{
    const int nblk = blockIdx.x;   // n tile: n0 = nblk*128 (n = s*768+d)
    const int tblk = blockIdx.y;   // t tile: t0 = tblk*256
    const int bb   = blockIdx.z;
    const int tid  = threadIdx.x;
    const int wave = tid >> 6, lane = tid & 63;
    const int mwz = wave >> 2, nwz = wave & 3;   // 2 x 4 wave grid
    const int quad = lane >> 4, l15 = lane & 15;

    // fragment-major LDS: [group of 16 rows][lane][8 bf16] = 1 KB/group
    __shared__ __align__(16) bf16 sA[8][64][8];    // 128 WtT rows (n)
    __shared__ __align__(16) bf16 sB[16][64][8];   // 256 xTc rows (t)

    // staging: wave w -> A-group w; B-groups 2w, 2w+1.
    // Fragment slot (g, lane): row = g*16 + (lane&15), k = (lane>>4)*8..+8.
    const int colk = quad * 8;
    const bf16* gA  = WtT + (size_t)(nblk * 128 + wave * 16 + l15) * C_ + colk;
    const bf16* gB0 = xTc + ((size_t)bb * T_ + tblk * 256 + 2 * wave * 16 + l15) * C_ + colk;
    const bf16* gB1 = gB0 + (size_t)16 * C_;

    f32x4 acc[4][4] = {};

    for (int k0 = 0; k0 < C_; k0 += 32) {
        __syncthreads();
        gload16(gA  + k0, &sA[wave][0][0]);
        gload16(gB0 + k0, &sB[2 * wave][0][0]);
        gload16(gB1 + k0, &sB[2 * wave + 1][0][0]);
        __syncthreads();

        bf16x8 af[4], bfr[4];
#pragma unroll
        for (int i = 0; i < 4; ++i) af[i]  = *(const bf16x8*)&sA[mwz * 4 + i][lane][0];
#pragma unroll
        for (int j = 0; j < 4; ++j) bfr[j] = *(const bf16x8*)&sB[nwz * 4 + j][lane][0];
#pragma unroll
        for (int i = 0; i < 4; ++i)
#pragma unroll
            for (int j = 0; j < 4; ++j)
                acc[i][j] = __builtin_amdgcn_mfma_f32_16x16x32_bf16(af[i], bfr[j], acc[i][j], 0, 0, 0);
    }

    // epilogue: D row = n-local (quad*4+r, 4 consecutive), col = t-local (l15).
#pragma unroll
    for (int i = 0; i < 4; ++i) {
        const int nb = mwz * 64 + i * 16 + quad * 4;
        const f32x4 bv = *(const f32x4*)&bias[(nblk % 6) * 128 + nb];
#pragma unroll
        for (int j = 0; j < 4; ++j) {
            const int t = tblk * 256 + nwz * 64 + j * 16 + l15;
            bf16x4 v;
#pragma unroll
            for (int r = 0; r < 4; ++r) v[r] = (bf16)(acc[i][j][r] + bv[r]);
            *(bf16x4*)&P[((size_t)bb * T_ + t) * (size_t)(S_ * C_) + (size_t)nblk * 128 + nb] = v;
        }
    }
}

// ---------- Phase 2: one wave per (bb, tp). p[s][n] = sum_d proj[t=tp-1-s][s][d]*tar[n][d]
// Lane l15==11 also writes the zero labels for its 12 output rows.
__global__ __launch_bounds__(256) void k_pred(
    const bf16* __restrict__ P, const bf16* __restrict__ yTc,
    const int* __restrict__ neg, float* __restrict__ out, int b0)
{
    const int widx = (blockIdx.x << 2) + (threadIdx.x >> 6);
    const int lane = threadIdx.x & 63;
    const int bb = widx >> 10, tp = widx & 1023;
    const int b = b0 + bb;
    const int quad = lane >> 4, l15 = lane & 15;

    // A row: m = s (pad rows clamped; their outputs are never stored)
    int sA = l15 < S_ ? l15 : S_ - 1;
    int tA = tp - 1 - sA;
    if (tA < 0) tA = 0;
    const bf16* arow = P + ((size_t)bb * T_ + tA) * (S_ * C_) + sA * C_ + quad * 8;

    // B row: n = copy (pad clamped)
    int ridx;
    if (l15 == 0)            ridx = bb * T_ + tp;
    else if (l15 < NCOPY)    ridx = neg[(size_t)b * (NNEG_ * T_) + (l15 - 1) * T_ + tp] - b0 * T_;
    else                     ridx = bb * T_ + tp;
    const bf16* brow = yTc + (size_t)ridx * C_ + quad * 8;

    f32x4 acc = {};
#pragma unroll 4
    for (int kt = 0; kt < C_ / 32; ++kt) {
        bf16x8 av = *(const bf16x8*)(arow + kt * 32);
        bf16x8 bv = *(const bf16x8*)(brow + kt * 32);
        acc = __builtin_amdgcn_mfma_f32_16x16x32_bf16(av, bv, acc, 0, 0, 0);
    }

#pragma unroll
    for (int r = 0; r < 4; ++r) {
        int s = quad * 4 + r;
        int t = tp - 1 - s;
        if (s < S_ && t >= 0) {
            int rowbase = s * (T_ - 1) - (s * (s - 1)) / 2;
            size_t row = (size_t)(rowbase + t) * B_ + b;
            if (l15 < NCOPY)       out[row * NCOPY + l15] = acc[r];
            else if (l15 == NCOPY) out[NPRED + row] = 0.0f;   // labels
        }
    }
}

extern "C" void kernel_launch(void* const* d_in, const int* in_sizes, int n_in,
                              void* d_out, int out_size, void* d_ws, size_t ws_size,
                              hipStream_t stream) {
    const float* x    = (const float*)d_in[0];
    const float* y    = (const float*)d_in[1];
    const float* W    = (const float*)d_in[2];
    const float* bias = (const float*)d_in[3];
    const int*   neg  = (const int*)d_in[4];
    float* out = (float*)d_out;

    const size_t offW    = (size_t)S_ * C_ * C_ * 2;        // 14,155,776
    const size_t perb_xy = (size_t)T_ * C_ * 2;             // 1,572,864
    const size_t perb_p  = (size_t)T_ * S_ * C_ * 2;        // 18,874,368
    const size_t perb    = 2 * perb_xy + perb_p;

    int bchunk = (int)((ws_size - offW) / perb);
    if (bchunk < 1) bchunk = 1;
    if (bchunk > B_) bchunk = B_;

    char* ws = (char*)d_ws;
    bf16* WtT = (bf16*)ws;
    bf16* xTc = (bf16*)(ws + offW);
    bf16* yTc = (bf16*)(ws + offW + (size_t)bchunk * perb_xy);
    bf16* P   = (bf16*)(ws + offW + (size_t)bchunk * perb_xy * 2);

    k_wt<<<dim3((C_ * C_ + 255) / 256), 256, 0, stream>>>(W, WtT);

    for (int b0 = 0; b0 < B_;) {
        int cb = bchunk < (B_ - b0) ? bchunk : (B_ - b0);
        k_tr2<<<dim3(T_ / 32, C_ / 32, 2 * cb), 256, 0, stream>>>(x, y, xTc, yTc, b0, cb);
        k_gemm<<<dim3(72, 4, cb), 512, 0, stream>>>(xTc, WtT, bias, P);
        k_pred<<<dim3(cb * 256), 256, 0, stream>>>(P, yTc, neg, out, b0);
        b0 += cb;
    }
}